// Round 11
// baseline (319.397 us; speedup 1.0000x reference)
//
#include <hip/hip_runtime.h>

typedef unsigned short u16;
typedef __attribute__((ext_vector_type(8))) short bf8;    // 8 x bf16 MFMA fragment
typedef __attribute__((ext_vector_type(4))) short s16x4;
typedef __attribute__((ext_vector_type(4))) float f32x4;
typedef __attribute__((ext_vector_type(4))) int   i32x4;
typedef __attribute__((ext_vector_type(2))) int   i32x2;

#define S_   96
#define T_   50
#define NSEQ 1536
#define NR   1537
#define XROW 520   // LDS row stride in shorts: 1040 B, 16B-aligned, 260 dwords
#define L2E   1.4426950408889634f
#define L2E2  2.8853900817779268f

__device__ __forceinline__ float bf2f(u16 u){ return __uint_as_float(((unsigned)u)<<16); }
__device__ __forceinline__ u16 f2bf(float f){
  unsigned u = __float_as_uint(f);
  u += 0x7fffu + ((u>>16)&1u);           // RNE
  return (u16)(u>>16);
}
// packed f32x2 -> bf16x2 (RNE), single HW instruction; bit-identical to f2bf
__device__ __forceinline__ int cvtpk(float lo, float hi){
  int r; asm("v_cvt_pk_bf16_f32 %0, %1, %2" : "=v"(r) : "v"(lo), "v"(hi)); return r;
}
#if __has_builtin(__builtin_amdgcn_exp2f)
__device__ __forceinline__ float exp2_(float x){ return __builtin_amdgcn_exp2f(x); }
#else
__device__ __forceinline__ float exp2_(float x){ return exp2f(x); }
#endif
// division-free; fine vs 2% threshold, NaN-safe at +-inf
__device__ __forceinline__ float sigm(float x){
  return __builtin_amdgcn_rcpf(1.f + __expf(-x));
}
__device__ __forceinline__ float tanh_(float x){
  return 1.f - 2.f*__builtin_amdgcn_rcpf(__expf(2.f*x) + 1.f);
}
// barrier that drains only LDS (lgkm), NOT in-flight global prefetch (vmcnt).
__device__ __forceinline__ void bar_lds(){
  asm volatile("s_waitcnt lgkmcnt(0)\n\ts_barrier" ::: "memory");
}

struct CvtArgs { const float* s[10]; u16* d[10]; };

// ---------------------------------------------------------------------------
// MEGA launch 1: lstm (blocks 0..191) + prep-cvt of NON-LSTM weights (blocks
// 192..607) + prep entry-lists (blocks 608..2143). The lstm<-prep dependency
// is broken by having each lstm block SELF-CONVERT its weights from f32
// (same f2bf RNE per element -> bit-identical Breg). lstm blocks first in
// the grid -> get CUs first; prep blocks drain on the 64 CUs without an lstm
// block. R2 lstm config (measured 71us after R9/R10 micro-opts) unchanged:
// 16 seqs/block, 8 waves, K-split pipeline, lgkm-only barrier 1/step,
// fma-folded exp2 gates, Phase-A peel, dead-tail skip.
// ---------------------------------------------------------------------------
__global__ __launch_bounds__(512, 2) void mega_kernel(
    const int* __restrict__ enc, const float* __restrict__ emb,
    const float* __restrict__ WihF, const float* __restrict__ WhhF, const float* __restrict__ bF,
    const float* __restrict__ WihB, const float* __restrict__ WhhB, const float* __restrict__ bB,
    u16* __restrict__ c_cat, u16* __restrict__ h_cat,
    CvtArgs ca,
    const int* __restrict__ par, const int* __restrict__ chi,
    const float* __restrict__ mask,
    int2* __restrict__ ent0, int* __restrict__ cnt0,
    int2* __restrict__ ent1, int* __restrict__ cnt1)
{
  __shared__ short xh[16*XROW];
  __shared__ int   toks[16*T_];
  __shared__ int   c0s, c1s;

  const int bid = blockIdx.x;
  const int tid = threadIdx.x;

  if (bid >= 192){
    if (bid < 608){
      // ---- non-LSTM weight cvt: elements [262144, 1114112), no permutation
      int e = 262144 + ((bid-192)*512 + tid)*4;
      int t, off;
      if (e < 327680){ int e2=e-262144; t = 4+(e2>>15); off = e2&32767; }
      else { int e3=e-327680; t = 6 + e3/196608; off = e3%196608; }
      f32x4 v = *reinterpret_cast<const f32x4*>(ca.s[t]+off);
      i32x2 o;
      o[0] = cvtpk(v[0], v[1]);
      o[1] = cvtpk(v[2], v[3]);
      *reinterpret_cast<i32x2*>(ca.d[t]+off) = o;
    } else {
      // ---- compacted active-partner lists (one row per block)
      const int rr = bid - 608;
      if (tid==0){ c0s=0; c1s=0; }
      __syncthreads();
      const int l = tid;
      if (l < S_){
        const int b = rr/S_, fx = rr%S_, base = b*S_*S_;
        int idx = base + l*S_ + fx;
        if (mask[idx] != 0.f){
          int p = atomicAdd(&c0s, 1);
          ent0[rr*S_ + p] = make_int2(chi[idx], par[idx]);
        }
        int jdx = base + fx*S_ + l;
        if (mask[jdx] != 0.f){
          int p = atomicAdd(&c1s, 1);
          ent1[rr*S_ + p] = make_int2(par[jdx], chi[jdx]);
        }
      }
      __syncthreads();
      if (tid==0){ cnt0[rr]=c0s; cnt1[rr]=c1s; }
    }
    return;
  }

  // ------------------------------- lstm path -------------------------------
  const int wave = tid>>6;
  const int lane = tid&63;
  const int dir  = bid/96;
  const int s0   = (bid%96)*16;

  const float* Wih = dir ? WihB : WihF;
  const float* Whh = dir ? WhhB : WhhF;
  const float* bb  = dir ? bB  : bF;

  for (int i=tid; i<16*T_; i+=512)
    toks[i] = enc[(s0 + i/T_)*T_ + (i%T_)];

  const int mL   = lane&15;
  const int quad = lane>>4;
  const int kb   = quad*8;

  // SELF-CONVERTED permuted weight fragments (bit-identical to prep's table:
  // same orig permutation, same f2bf RNE). Breg[n][0..3]=x, [4..7]=h.
  // sbias[n] = bias*(-L2E) for i/f/o, bias*(2L2E) for g (f32-only; R9 opt).
  bf8 Breg[4][8];
  f32x4 sbias[4];
  #pragma unroll
  for (int n=0;n<4;n++){
    int colp = wave*64 + n*16 + mL;
    int orig = ((colp>>4)&3)*128 + ((colp>>6)<<4) + (colp&15);
    f32x4 bv = *reinterpret_cast<const f32x4*>(bb + n*128 + wave*16 + quad*4);
    float sc = (n==2) ? L2E2 : -L2E;
    #pragma unroll
    for (int i=0;i<4;i++) sbias[n][i] = bv[i]*sc;
    #pragma unroll
    for (int ks=0;ks<8;ks++){
      int k = ks*32 + kb;
      const float* pf = (k<128) ? (Wih + orig*128 + k) : (Whh + orig*128 + (k-128));
      f32x4 w0 = *reinterpret_cast<const f32x4*>(pf);
      f32x4 w1 = *reinterpret_cast<const f32x4*>(pf+4);
      i32x4 q;
      q[0]=cvtpk(w0[0],w0[1]); q[1]=cvtpk(w0[2],w0[3]);
      q[2]=cvtpk(w1[0],w1[1]); q[3]=cvtpk(w1[2],w1[3]);
      Breg[n][ks] = *reinterpret_cast<bf8*>(&q);
      asm volatile("" : "+v"(Breg[n][ks]));
    }
  }

  if (tid<256){
    int r = tid>>4, c = tid&15;
    *reinterpret_cast<i32x4*>(&xh[r*XROW + 256 + c*8]) = (i32x4){0,0,0,0};
  }

  const int srow = tid>>5, schunk = tid&31;
  float cst[4] = {0.f,0.f,0.f,0.f};
  float hst[4] = {0.f,0.f,0.f,0.f};

  __syncthreads();

  {
    int tok0 = toks[srow*T_ + (dir ? (T_-1) : 0)];
    f32x4 x0 = *reinterpret_cast<const f32x4*>(emb + tok0*128 + schunk*4);
    int tok1 = toks[srow*T_ + (dir ? (T_-2) : 1)];
    f32x4 x1 = *reinterpret_cast<const f32x4*>(emb + tok1*128 + schunk*4);
    i32x2 p0; p0[0]=cvtpk(x0[0],x0[1]); p0[1]=cvtpk(x0[2],x0[3]);
    i32x2 p1; p1[0]=cvtpk(x1[0],x1[1]); p1[1]=cvtpk(x1[2],x1[3]);
    *reinterpret_cast<i32x2*>(&xh[srow*XROW +       schunk*4]) = p0;
    *reinterpret_cast<i32x2*>(&xh[srow*XROW + 128 + schunk*4]) = p1;
  }
  f32x4 xvA, xvB;
  {
    int tA = toks[srow*T_ + (dir ? (T_-3) : 2)];
    xvA = *reinterpret_cast<const f32x4*>(emb + tA*128 + schunk*4);
    int tB = toks[srow*T_ + (dir ? (T_-4) : 3)];
    xvB = *reinterpret_cast<const f32x4*>(emb + tB*128 + schunk*4);
  }
  __syncthreads();

  // pre-loop: accx(0) = Wih @ x(0)
  f32x4 accx[4];
  #pragma unroll
  for (int n=0;n<4;n++) accx[n] = (f32x4){0.f,0.f,0.f,0.f};
  #pragma unroll
  for (int ks=0;ks<4;ks++){
    bf8 b = *reinterpret_cast<const bf8*>(&xh[mL*XROW + ks*32 + kb]);
    #pragma unroll
    for (int n=0;n<4;n++)
      accx[n] = __builtin_amdgcn_mfma_f32_16x16x32_bf16(Breg[n][ks], b, accx[n], 0,0,0);
  }
  bar_lds();  // RACE FIX: pre-loop x-slot-0 reads before step-0 restage.

  for (int t=0;t<T_;t++){
    const int cb = t&1, nb = cb^1;

    // Phase A: peel (first h-MFMA takes accx as C-in) + 3 more
    f32x4 acc[4];
    {
      bf8 b = *reinterpret_cast<const bf8*>(&xh[mL*XROW + 256 + cb*128 + kb]);
      #pragma unroll
      for (int n=0;n<4;n++)
        acc[n] = __builtin_amdgcn_mfma_f32_16x16x32_bf16(Breg[n][4], b, accx[n], 0,0,0);
    }
    #pragma unroll
    for (int ks=1;ks<4;ks++){
      bf8 b = *reinterpret_cast<const bf8*>(&xh[mL*XROW + 256 + cb*128 + ks*32 + kb]);
      #pragma unroll
      for (int n=0;n<4;n++)
        acc[n] = __builtin_amdgcn_mfma_f32_16x16x32_bf16(Breg[n][4+ks], b, acc[n], 0,0,0);
    }

    if (t+2 < T_){
      i32x2 p; p[0]=cvtpk(xvA[0],xvA[1]); p[1]=cvtpk(xvA[2],xvA[3]);
      *reinterpret_cast<i32x2*>(&xh[srow*XROW + cb*128 + schunk*4]) = p;
    }
    xvA = xvB;
    if (t+4 < T_){
      int tok = toks[srow*T_ + (dir ? (T_-5-t) : (t+4))];
      xvB = *reinterpret_cast<const f32x4*>(emb + tok*128 + schunk*4);
    }

    // Phase B: accx(t+1) = Wih @ x(t+1)
    if (t+1 < T_){
      #pragma unroll
      for (int n=0;n<4;n++) accx[n] = (f32x4){0.f,0.f,0.f,0.f};
      #pragma unroll
      for (int ks=0;ks<4;ks++){
        bf8 b = *reinterpret_cast<const bf8*>(&xh[mL*XROW + nb*128 + ks*32 + kb]);
        #pragma unroll
        for (int n=0;n<4;n++)
          accx[n] = __builtin_amdgcn_mfma_f32_16x16x32_bf16(Breg[n][ks], b, accx[n], 0,0,0);
      }
    }

    // cell update: fma-folded exp2 gates (R9/R10 verified, absmax 384)
    float hv4[4];
    #pragma unroll
    for (int i=0;i<4;i++){
      float si = __builtin_amdgcn_rcpf(1.f + exp2_(fmaf(acc[0][i], -L2E, sbias[0][i])));
      float sf = __builtin_amdgcn_rcpf(1.f + exp2_(fmaf(acc[1][i], -L2E, sbias[1][i])));
      float so = __builtin_amdgcn_rcpf(1.f + exp2_(fmaf(acc[3][i], -L2E, sbias[3][i])));
      float tg = 1.f - 2.f*__builtin_amdgcn_rcpf(exp2_(fmaf(acc[2][i], L2E2, sbias[2][i])) + 1.f);
      float c  = sf*cst[i] + si*tg;
      float th = 1.f - 2.f*__builtin_amdgcn_rcpf(exp2_(c*L2E2) + 1.f);
      float h  = so*th;
      cst[i]=c; hst[i]=h; hv4[i]=h;
    }
    if (t != T_-1){
      i32x2 hp;
      hp[0]=cvtpk(hv4[0],hv4[1]); hp[1]=cvtpk(hv4[2],hv4[3]);
      *reinterpret_cast<i32x2*>(&xh[mL*XROW + 256 + nb*128 + wave*16 + quad*4]) = hp;
      bar_lds();
    }
  }

  {
    const int ch = wave*16 + quad*4;
    const int gs = s0 + mL;
    i32x2 cp_, hp_;
    cp_[0]=cvtpk(cst[0],cst[1]); cp_[1]=cvtpk(cst[2],cst[3]);
    hp_[0]=cvtpk(hst[0],hst[1]); hp_[1]=cvtpk(hst[2],hst[3]);
    *reinterpret_cast<i32x2*>(c_cat + gs*256 + dir*128 + ch) = cp_;
    *reinterpret_cast<i32x2*>(h_cat + gs*256 + dir*128 + ch) = hp_;
  }
}

// ---------------------------------------------------------------------------
// Launch 2: reduce FUSED into gates0. Both are row-local: hidden[g] =
// relu-reduce(cat[g-1]) and gates0 block (bx,by) reads hidden rows
// 32bx..32bx+31 only. Each block recomputes its own 32 hidden rows (12x
// redundant across by; global writes are byte-identical -> benign races),
// keeps a bf16 copy in LDS, then runs the gates GEMM reading A from LDS.
// Per-output K-order identical to standalone reduce/gates -> bit-exact.
// Clamps: A-row for g=0 discarded (v forced 0); rows past 1535 clamp to
// 1535 so LDS slots past g=1536 hold hidden[1536] (matches gates' arow min).
// ---------------------------------------------------------------------------
__global__ __launch_bounds__(256) void rgates_kernel(
    const u16* __restrict__ c_cat, const u16* __restrict__ h_cat,
    const u16* __restrict__ Wc,  const float* __restrict__ bc,
    const u16* __restrict__ Whr, const float* __restrict__ bhr,
    float* __restrict__ hidf, u16* __restrict__ hidb,
    const u16* __restrict__ Wi, const u16* __restrict__ Wh,
    const float* __restrict__ bi, const float* __restrict__ bh,
    u16* __restrict__ gi, u16* __restrict__ gh)
{
  __shared__ u16 hl[32][264];   // bf16 hidden rows g0..g0+31 (row 528B, 16B-mult)

  const int tid=threadIdx.x, wave=tid>>6, lane=tid&63;
  const int mL=lane&15, quad=lane>>4, kb=quad*8;
  const int g0 = blockIdx.x*32;

  // ---- reduce part: fill hl + global hidf/hidb (2 passes of 16 rows) ----
  {
    const u16* A    = (wave<2) ? c_cat : h_cat;
    const u16* W    = (wave<2) ? Wc  : Whr;
    const float* bv = (wave<2) ? bc  : bhr;
    const int nb_   = (wave&1)*64;
    const int obase = (wave<2) ? 0 : 128;

    #pragma unroll
    for (int p=0;p<2;p++){
      const int base = g0 + p*16 - 1;          // cat-row base (may be -1 / >1535)
      f32x4 acc[4];
      #pragma unroll
      for (int nt=0;nt<4;nt++) acc[nt] = (f32x4){0.f,0.f,0.f,0.f};

      int ar = base + mL;
      ar = (ar < 0) ? 0 : ((ar > 1535) ? 1535 : ar);

      #pragma unroll
      for (int ks=0;ks<8;ks++){
        int k = ks*32 + kb;
        bf8 bfr[4];
        #pragma unroll
        for (int nt=0;nt<4;nt++)
          bfr[nt] = *reinterpret_cast<const bf8*>(W + (nb_+nt*16+mL)*256 + k);
        bf8 a = *reinterpret_cast<const bf8*>(A + ar*256 + k);
        #pragma unroll
        for (int nt=0;nt<4;nt++)
          acc[nt] = __builtin_amdgcn_mfma_f32_16x16x32_bf16(a, bfr[nt], acc[nt], 0,0,0);
      }
      float biasv[4];
      #pragma unroll
      for (int nt=0;nt<4;nt++) biasv[nt] = bv[nb_+nt*16+mL];
      #pragma unroll
      for (int nt=0;nt<4;nt++){
        int col = obase + nb_ + nt*16 + mL;
        #pragma unroll
        for (int i=0;i<4;i++){
          int g = base + quad*4 + i + 1;       // hidden row in [g0, g0+31]
          float v = fmaxf(acc[nt][i] + biasv[nt], 0.f);
          if (g == 0) v = 0.f;                 // zero row (clamped A discarded)
          u16 hv16 = f2bf(v);
          hl[g - g0][col] = hv16;
          if (g <= 1536){
            hidf[g*256 + col] = v;
            hidb[g*256 + col] = hv16;
          }
        }
      }
    }
  }
  __syncthreads();

  // ---- gates part (R7/R10 tiling; A from LDS) ----
  const int m0 = g0;
  const int n0 = blockIdx.y*128 + wave*32;   // blockIdx.y in [0,12)
  const bool isI = (n0 < 768);
  const u16* W    = isI ? Wi : Wh;
  const float* bv = isI ? bi : bh;
  u16* out        = isI ? gi : gh;
  const int nbc   = isI ? n0 : (n0-768);

  int aslot[2];
  #pragma unroll
  for (int mt=0;mt<2;mt++) aslot[mt] = min(m0+mt*16+mL, NR-1) - g0;

  f32x4 acc[2][2];
  #pragma unroll
  for (int mt=0;mt<2;mt++)
    #pragma unroll
    for (int nt=0;nt<2;nt++) acc[mt][nt] = (f32x4){0.f,0.f,0.f,0.f};

  #pragma unroll
  for (int ks=0;ks<8;ks++){
    int k = ks*32 + kb;
    bf8 bfr[2];
    #pragma unroll
    for (int nt=0;nt<2;nt++)
      bfr[nt] = *reinterpret_cast<const bf8*>(W + (nbc+nt*16+mL)*256 + k);
    #pragma unroll
    for (int mt=0;mt<2;mt++){
      bf8 a = *reinterpret_cast<const bf8*>(&hl[aslot[mt]][k]);
      #pragma unroll
      for (int nt=0;nt<2;nt++)
        acc[mt][nt] = __builtin_amdgcn_mfma_f32_16x16x32_bf16(a, bfr[nt], acc[mt][nt], 0,0,0);
    }
  }
  const int row0 = quad*4;
  float biasv[2];
  #pragma unroll
  for (int nt=0;nt<2;nt++) biasv[nt] = bv[nbc+nt*16+mL];
  #pragma unroll
  for (int mt=0;mt<2;mt++){
    #pragma unroll
    for (int nt=0;nt<2;nt++){
      #pragma unroll
      for (int i=0;i<4;i++){
        int r = m0 + mt*16 + row0 + i;
        if (r < NR)
          out[r*768 + nbc + nt*16 + mL] = f2bf(acc[mt][nt][i] + biasv[nt]);
      }
    }
  }
}

// ---------------------------------------------------------------------------
// Stage 3 (x3, iterations 1..3): gi = hidden@Wi.T + bi, gh = hidden@Wh.T + bh
// R7 shape: (49,12)x256, nt=2 -> 2.3 waves/SIMD.
// ---------------------------------------------------------------------------
__global__ __launch_bounds__(256) void gates_gemm_kernel(
    const u16* __restrict__ hidb,
    const u16* __restrict__ Wi, const u16* __restrict__ Wh,
    const float* __restrict__ bi, const float* __restrict__ bh,
    u16* __restrict__ gi, u16* __restrict__ gh)
{
  const int tid=threadIdx.x, wave=tid>>6, lane=tid&63;
  const int mL=lane&15, quad=lane>>4, kb=quad*8;
  const int m0 = blockIdx.x*32;
  const int n0 = blockIdx.y*128 + wave*32;   // blockIdx.y in [0,12)
  const bool isI = (n0 < 768);
  const u16* W    = isI ? Wi : Wh;
  const float* bv = isI ? bi : bh;
  u16* out        = isI ? gi : gh;
  const int nbc   = isI ? n0 : (n0-768);

  int arow[2];
  #pragma unroll
  for (int mt=0;mt<2;mt++) arow[mt] = min(m0+mt*16+mL, NR-1);

  f32x4 acc[2][2];
  #pragma unroll
  for (int mt=0;mt<2;mt++)
    #pragma unroll
    for (int nt=0;nt<2;nt++) acc[mt][nt] = (f32x4){0.f,0.f,0.f,0.f};

  #pragma unroll
  for (int ks=0;ks<8;ks++){
    int k = ks*32 + kb;
    bf8 bfr[2];
    #pragma unroll
    for (int nt=0;nt<2;nt++)
      bfr[nt] = *reinterpret_cast<const bf8*>(W + (nbc+nt*16+mL)*256 + k);
    #pragma unroll
    for (int mt=0;mt<2;mt++){
      bf8 a = *reinterpret_cast<const bf8*>(hidb + arow[mt]*256 + k);
      #pragma unroll
      for (int nt=0;nt<2;nt++)
        acc[mt][nt] = __builtin_amdgcn_mfma_f32_16x16x32_bf16(a, bfr[nt], acc[mt][nt], 0,0,0);
    }
  }
  const int row0 = quad*4;
  float biasv[2];
  #pragma unroll
  for (int nt=0;nt<2;nt++) biasv[nt] = bv[nbc+nt*16+mL];
  #pragma unroll
  for (int mt=0;mt<2;mt++){
    #pragma unroll
    for (int nt=0;nt<2;nt++){
      #pragma unroll
      for (int i=0;i<4;i++){
        int r = m0 + mt*16 + row0 + i;
        if (r < NR)
          out[r*768 + nbc + nt*16 + mL] = f2bf(acc[mt][nt][i] + biasv[nt]);
      }
    }
  }
}

// ---------------------------------------------------------------------------
// Stage 4 (x4): R2/R7 version (measured best). Block per output row; partners
// split across 8 waves (512 thr); GRU elementwise fp32; LDS cross-wave sum;
// L2-norm scale; double-buffered hidden update. R6 lesson: 1537 small blocks
// beat one-wave-per-row — gather latency needs wave oversubscription.
// ---------------------------------------------------------------------------
__global__ __launch_bounds__(512) void pair_kernel(
    const u16* __restrict__ gi, const u16* __restrict__ gh,
    const float* __restrict__ hin,
    float* __restrict__ hout, u16* __restrict__ bout, float* __restrict__ dout,
    const int2* __restrict__ ent, const int* __restrict__ cnt)
{
  const int r = blockIdx.x;
  const int tid = threadIdx.x, wave = tid>>6, lane = tid&63;
  __shared__ float part[8][260];
  __shared__ float ssum[4];
  if (r==0){
    if (tid<256){
      hout[tid]=0.f; bout[tid]=0;
      if (dout) dout[tid]=0.f;
    }
    return;
  }
  const int rr = r-1;
  const int n  = cnt[rr];
  const int2* e = ent + rr*S_;
  const int ch0 = lane*4;

  float a0=0.f, a1=0.f, a2=0.f, a3=0.f;
  for (int k=wave; k<n; k+=8){
    int2 pr = e[k];
    const u16* gx = gi + pr.x*768 + ch0;
    const u16* gy = gh + pr.y*768 + ch0;
    s16x4 vi0 = *reinterpret_cast<const s16x4*>(gx);
    s16x4 vi1 = *reinterpret_cast<const s16x4*>(gx+256);
    s16x4 vi2 = *reinterpret_cast<const s16x4*>(gx+512);
    s16x4 vh0 = *reinterpret_cast<const s16x4*>(gy);
    s16x4 vh1 = *reinterpret_cast<const s16x4*>(gy+256);
    s16x4 vh2 = *reinterpret_cast<const s16x4*>(gy+512);
    f32x4 hv  = *reinterpret_cast<const f32x4*>(hin + pr.y*256 + ch0);
    float o[4];
    #pragma unroll
    for (int i=0;i<4;i++){
      float rg = sigm(bf2f((u16)vi0[i]) + bf2f((u16)vh0[i]));
      float zg = sigm(bf2f((u16)vi1[i]) + bf2f((u16)vh1[i]));
      float ng = tanh_(bf2f((u16)vi2[i]) + rg*bf2f((u16)vh2[i]));
      o[i] = (1.f-zg)*ng + zg*hv[i];
    }
    a0 += o[0]; a1 += o[1]; a2 += o[2]; a3 += o[3];
  }
  *reinterpret_cast<f32x4*>(&part[wave][ch0]) = (f32x4){a0,a1,a2,a3};
  __syncthreads();

  if (tid < 256){
    float tot = part[0][tid] + part[1][tid] + part[2][tid] + part[3][tid]
              + part[4][tid] + part[5][tid] + part[6][tid] + part[7][tid];
    part[0][tid] = tot;                 // stash for epilogue
    float sq = tot*tot;
    #pragma unroll
    for (int off=32; off>0; off>>=1) sq += __shfl_xor(sq, off, 64);
    if (lane==0) ssum[wave] = sq;
  }
  __syncthreads();
  if (tid < 256){
    float tot = part[0][tid];
    float v  = sqrtf(ssum[0]+ssum[1]+ssum[2]+ssum[3]);
    float sc = (v + 0.25f)*__builtin_amdgcn_rcpf(v + 1.f);
    float nv = hin[r*256 + tid] + tot*sc;
    hout[r*256 + tid] = nv;
    bout[r*256 + tid] = f2bf(nv);
    if (dout) dout[r*256 + tid] = nv;
  }
}

// ---------------------------------------------------------------------------
extern "C" void kernel_launch(void* const* d_in, const int* in_sizes, int n_in,
                              void* d_out, int out_size, void* d_ws, size_t ws_size,
                              hipStream_t stream)
{
  const int*   enc  = (const int*)  d_in[0];
  const int*   spar = (const int*)  d_in[1];
  const int*   schi = (const int*)  d_in[2];
  const float* mask = (const float*)d_in[3];
  const float* emb  = (const float*)d_in[4];
  const float* WihF = (const float*)d_in[5];
  const float* WhhF = (const float*)d_in[6];
  const float* bF   = (const float*)d_in[7];
  const float* WihB = (const float*)d_in[8];
  const float* WhhB = (const float*)d_in[9];
  const float* bB   = (const float*)d_in[10];
  const float* Wc   = (const float*)d_in[11];
  const float* bc   = (const float*)d_in[12];
  const float* Whr  = (const float*)d_in[13];
  const float* bhr  = (const float*)d_in[14];
  const float* WiCP = (const float*)d_in[15];
  const float* WhCP = (const float*)d_in[16];
  const float* biCP = (const float*)d_in[17];
  const float* bhCP = (const float*)d_in[18];
  const float* WiPC = (const float*)d_in[19];
  const float* WhPC = (const float*)d_in[20];
  const float* biPC = (const float*)d_in[21];
  const float* bhPC = (const float*)d_in[22];

  // workspace layout (~14.8 MB)
  char* ws = (char*)d_ws;
  u16*   c_cat = (u16*)  (ws + 0);          // 1536*256 bf16
  u16*   h_cat = (u16*)  (ws + 786432);
  float* hf0   = (float*)(ws + 1572864);    // 1537*256 f32
  float* hf1   = (float*)(ws + 3146752);
  u16*   hb    = (u16*)  (ws + 4720640);    // 1537*256 bf16 (single buffer)
  u16*   gi    = (u16*)  (ws + 5507584);    // 1537*768 bf16
  u16*   gh    = (u16*)  (ws + 7868416);
  u16*   wbf   = (u16*)  (ws + 10229248);   // bf16 weights (1114112 elems)
  int2*  ent0  = (int2*) (ws + 12457472);   // 1536*96 int2
  int2*  ent1  = (int2*) (ws + 13637120);
  int*   cnt0  = (int*)  (ws + 14816768);
  int*   cnt1  = (int*)  (ws + 14822912);
  float* out   = (float*)d_out;

  u16* bWc   = wbf + 262144;
  u16* bWhr  = wbf + 294912;
  u16* bWiCP = wbf + 327680;
  u16* bWhCP = wbf + 524288;
  u16* bWiPC = wbf + 720896;
  u16* bWhPC = wbf + 917504;

  CvtArgs ca;
  ca.s[0]=WihF; ca.s[1]=WhhF; ca.s[2]=WihB; ca.s[3]=WhhB;
  ca.s[4]=Wc;   ca.s[5]=Whr;
  ca.s[6]=WiCP; ca.s[7]=WhCP; ca.s[8]=WiPC; ca.s[9]=WhPC;
  ca.d[0]=wbf;        ca.d[1]=wbf+65536;  ca.d[2]=wbf+131072; ca.d[3]=wbf+196608;
  ca.d[4]=bWc;   ca.d[5]=bWhr;
  ca.d[6]=bWiCP; ca.d[7]=bWhCP; ca.d[8]=bWiPC; ca.d[9]=bWhPC;

  // Launch 1: lstm (self-converting weights) + prep cvt + entry lists
  mega_kernel<<<dim3(192+416+1536), dim3(512), 0, stream>>>(
      enc, emb, WihF, WhhF, bF, WihB, WhhB, bB, c_cat, h_cat,
      ca, spar, schi, mask, ent0, cnt0, ent1, cnt1);

  // Launch 2: reduce fused into gates(it=0)
  rgates_kernel<<<dim3(49,12), dim3(256), 0, stream>>>(
      c_cat, h_cat, bWc, bc, bWhr, bhr, hf0, hb,
      bWiCP, bWhCP, biCP, bhCP, gi, gh);

  float* hfb[2] = {hf0,hf1};
  int cur = 0;
  for (int it=0; it<4; it++){
    if (it > 0){
      const u16* Wi   = (it<2)?bWiCP:bWiPC;
      const u16* Wh   = (it<2)?bWhCP:bWhPC;
      const float* bi = (it<2)?biCP:biPC;
      const float* bh = (it<2)?bhCP:bhPC;
      gates_gemm_kernel<<<dim3(49,12), dim3(256), 0, stream>>>(
          hb, Wi,Wh,bi,bh, gi,gh);
    }
    int nxt = cur^1;
    pair_kernel<<<dim3(NR), dim3(512), 0, stream>>>(
        gi,gh, hfb[cur], hfb[nxt], hb,
        (it==3)?out:(float*)nullptr,
        (it<2)?ent0:ent1, (it<2)?cnt0:cnt1);
    cur = nxt;
  }
}

// Round 12
// 305.514 us; speedup vs baseline: 1.0454x; 1.0454x over previous
//
#include <hip/hip_runtime.h>

typedef unsigned short u16;
typedef __attribute__((ext_vector_type(8))) short bf8;    // 8 x bf16 MFMA fragment
typedef __attribute__((ext_vector_type(4))) short s16x4;
typedef __attribute__((ext_vector_type(4))) float f32x4;
typedef __attribute__((ext_vector_type(4))) int   i32x4;
typedef __attribute__((ext_vector_type(2))) int   i32x2;

#define S_   96
#define T_   50
#define NSEQ 1536
#define NR   1537
#define XROW 520   // LDS row stride in shorts: 1040 B, 16B-aligned, 260 dwords
#define L2E   1.4426950408889634f
#define L2E2  2.8853900817779268f

__device__ __forceinline__ float bf2f(u16 u){ return __uint_as_float(((unsigned)u)<<16); }
__device__ __forceinline__ u16 f2bf(float f){
  unsigned u = __float_as_uint(f);
  u += 0x7fffu + ((u>>16)&1u);           // RNE
  return (u16)(u>>16);
}
// packed f32x2 -> bf16x2 (RNE), single HW instruction; bit-identical to f2bf
__device__ __forceinline__ int cvtpk(float lo, float hi){
  int r; asm("v_cvt_pk_bf16_f32 %0, %1, %2" : "=v"(r) : "v"(lo), "v"(hi)); return r;
}
#if __has_builtin(__builtin_amdgcn_exp2f)
__device__ __forceinline__ float exp2_(float x){ return __builtin_amdgcn_exp2f(x); }
#else
__device__ __forceinline__ float exp2_(float x){ return exp2f(x); }
#endif
// division-free; fine vs 2% threshold, NaN-safe at +-inf
__device__ __forceinline__ float sigm(float x){
  return __builtin_amdgcn_rcpf(1.f + __expf(-x));
}
__device__ __forceinline__ float tanh_(float x){
  return 1.f - 2.f*__builtin_amdgcn_rcpf(__expf(2.f*x) + 1.f);
}
// barrier that drains only LDS (lgkm), NOT in-flight global prefetch (vmcnt).
__device__ __forceinline__ void bar_lds(){
  asm volatile("s_waitcnt lgkmcnt(0)\n\ts_barrier" ::: "memory");
}

// ---------------------------------------------------------------------------
// Stage 0 (fused): blocks [0,1088) convert fp32 weights to bf16 (LSTM weights
// row-permuted); blocks [1088, 1088+NSEQ) build compacted active-partner
// lists. NO pre-scaling of weights (R1 lesson: absmax headroom ~9%; bf16
// weight-bit changes are fatal). R11 lesson: fusing prep into lstm costs more
// (+8us kernel) than the saved launch (~3us) — keep separate.
// ---------------------------------------------------------------------------
struct CvtArgs { const float* s[10]; u16* d[10]; };
__global__ __launch_bounds__(256) void prep_kernel(CvtArgs a,
    const int* __restrict__ par, const int* __restrict__ chi,
    const float* __restrict__ mask,
    int2* __restrict__ ent0, int* __restrict__ cnt0,
    int2* __restrict__ ent1, int* __restrict__ cnt1)
{
  if (blockIdx.x < 1088){
    int e = (blockIdx.x*256 + threadIdx.x)*4;
    if (e >= 1114112) return;
    int t, off;
    if (e < 262144){ t = e>>16; off = e & 65535; }
    else if (e < 327680){ int e2=e-262144; t = 4+(e2>>15); off = e2&32767; }
    else { int e3=e-327680; t = 6 + e3/196608; off = e3%196608; }
    int src = off;
    if (t < 4){
      int colp = off>>7, k = off&127;
      int orig = ((colp>>4)&3)*128 + ((colp>>6)<<4) + (colp&15);
      src = orig*128 + k;
    }
    f32x4 v = *reinterpret_cast<const f32x4*>(a.s[t]+src);
    i32x2 o;
    o[0] = cvtpk(v[0], v[1]);
    o[1] = cvtpk(v[2], v[3]);
    *reinterpret_cast<i32x2*>(a.d[t]+off) = o;
  } else {
    const int rr = blockIdx.x - 1088;
    __shared__ int c0s, c1s;
    if (threadIdx.x==0){ c0s=0; c1s=0; }
    __syncthreads();
    const int l = threadIdx.x;
    if (l < S_){
      const int b = rr/S_, fx = rr%S_, base = b*S_*S_;
      int idx = base + l*S_ + fx;
      if (mask[idx] != 0.f){
        int p = atomicAdd(&c0s, 1);
        ent0[rr*S_ + p] = make_int2(chi[idx], par[idx]);
      }
      int jdx = base + fx*S_ + l;
      if (mask[jdx] != 0.f){
        int p = atomicAdd(&c1s, 1);
        ent1[rr*S_ + p] = make_int2(par[jdx], chi[jdx]);
      }
    }
    __syncthreads();
    if (threadIdx.x==0){ cnt0[rr]=c0s; cnt1[rr]=c1s; }
  }
}

// ---------------------------------------------------------------------------
// Stage 1: bidirectional LSTM final states. R2 configuration (measured 71us
// after R9/R10 micro-opts): 16 seqs/block, 8 waves, grid (96,2)x512, weights
// register-resident (asm-pinned), K-split pipeline, lgkm-only barrier 1/step,
// fma-folded exp2 gates, Phase-A peel, dead-tail skip.
// R3/R4: 4 weight-pinned waves/SIMD impossible (VGPR); 32-seq ILP blocks
// halve active CUs at a net loss. R8/R9: grid-barrier fusion condemned
// (per-block agent fences wipe L2 -> 130MB refetch). R11: prep-fusion and
// reduce-fusion both net-negative. This is the best measured point.
// ---------------------------------------------------------------------------
__global__ __launch_bounds__(512, 2) void lstm_kernel(
    const int* __restrict__ enc, const float* __restrict__ emb,
    const u16* __restrict__ WihF, const u16* __restrict__ WhhF, const float* __restrict__ bF,
    const u16* __restrict__ WihB, const u16* __restrict__ WhhB, const float* __restrict__ bB,
    u16* __restrict__ c_cat, u16* __restrict__ h_cat)
{
  __shared__ short xh[16*XROW];
  __shared__ int   toks[16*T_];

  const int tid  = threadIdx.x;
  const int wave = tid>>6;
  const int lane = tid&63;
  const int dir  = blockIdx.y;
  const int s0   = blockIdx.x*16;

  const u16* Wih = dir ? WihB : WihF;
  const u16* Whh = dir ? WhhB : WhhF;
  const float* bb = dir ? bB  : bF;

  for (int i=tid; i<16*T_; i+=512)
    toks[i] = enc[(s0 + i/T_)*T_ + (i%T_)];

  const int mL   = lane&15;
  const int quad = lane>>4;
  const int kb   = quad*8;

  // permuted weight fragments (A-operand layout), pinned.
  // Breg[n][0..3] = x-weights (k<128), Breg[n][4..7] = h-weights.
  // sbias[n] = bias*(-L2E) for i/f/o, bias*(2L2E) for g (f32-only; R9 opt).
  bf8 Breg[4][8];
  f32x4 sbias[4];
  #pragma unroll
  for (int n=0;n<4;n++){
    int colp = wave*64 + n*16 + mL;
    f32x4 bv = *reinterpret_cast<const f32x4*>(bb + n*128 + wave*16 + quad*4);
    float sc = (n==2) ? L2E2 : -L2E;
    #pragma unroll
    for (int i=0;i<4;i++) sbias[n][i] = bv[i]*sc;
    #pragma unroll
    for (int ks=0;ks<8;ks++){
      int k = ks*32 + kb;
      const u16* p = (k<128) ? (Wih + colp*128 + k) : (Whh + colp*128 + (k-128));
      Breg[n][ks] = *reinterpret_cast<const bf8*>(p);
      asm volatile("" : "+v"(Breg[n][ks]));
    }
  }

  if (tid<256){
    int r = tid>>4, c = tid&15;
    *reinterpret_cast<i32x4*>(&xh[r*XROW + 256 + c*8]) = (i32x4){0,0,0,0};
  }

  const int srow = tid>>5, schunk = tid&31;
  float cst[4] = {0.f,0.f,0.f,0.f};
  float hst[4] = {0.f,0.f,0.f,0.f};

  __syncthreads();

  {
    int tok0 = toks[srow*T_ + (dir ? (T_-1) : 0)];
    f32x4 x0 = *reinterpret_cast<const f32x4*>(emb + tok0*128 + schunk*4);
    int tok1 = toks[srow*T_ + (dir ? (T_-2) : 1)];
    f32x4 x1 = *reinterpret_cast<const f32x4*>(emb + tok1*128 + schunk*4);
    i32x2 p0; p0[0]=cvtpk(x0[0],x0[1]); p0[1]=cvtpk(x0[2],x0[3]);
    i32x2 p1; p1[0]=cvtpk(x1[0],x1[1]); p1[1]=cvtpk(x1[2],x1[3]);
    *reinterpret_cast<i32x2*>(&xh[srow*XROW +       schunk*4]) = p0;
    *reinterpret_cast<i32x2*>(&xh[srow*XROW + 128 + schunk*4]) = p1;
  }
  f32x4 xvA, xvB;
  {
    int tA = toks[srow*T_ + (dir ? (T_-3) : 2)];
    xvA = *reinterpret_cast<const f32x4*>(emb + tA*128 + schunk*4);
    int tB = toks[srow*T_ + (dir ? (T_-4) : 3)];
    xvB = *reinterpret_cast<const f32x4*>(emb + tB*128 + schunk*4);
  }
  __syncthreads();

  // pre-loop: accx(0) = Wih @ x(0)
  f32x4 accx[4];
  #pragma unroll
  for (int n=0;n<4;n++) accx[n] = (f32x4){0.f,0.f,0.f,0.f};
  #pragma unroll
  for (int ks=0;ks<4;ks++){
    bf8 b = *reinterpret_cast<const bf8*>(&xh[mL*XROW + ks*32 + kb]);
    #pragma unroll
    for (int n=0;n<4;n++)
      accx[n] = __builtin_amdgcn_mfma_f32_16x16x32_bf16(Breg[n][ks], b, accx[n], 0,0,0);
  }
  bar_lds();  // RACE FIX: pre-loop x-slot-0 reads before step-0 restage.

  for (int t=0;t<T_;t++){
    const int cb = t&1, nb = cb^1;

    // Phase A: peel (first h-MFMA takes accx as C-in) + 3 more
    f32x4 acc[4];
    {
      bf8 b = *reinterpret_cast<const bf8*>(&xh[mL*XROW + 256 + cb*128 + kb]);
      #pragma unroll
      for (int n=0;n<4;n++)
        acc[n] = __builtin_amdgcn_mfma_f32_16x16x32_bf16(Breg[n][4], b, accx[n], 0,0,0);
    }
    #pragma unroll
    for (int ks=1;ks<4;ks++){
      bf8 b = *reinterpret_cast<const bf8*>(&xh[mL*XROW + 256 + cb*128 + ks*32 + kb]);
      #pragma unroll
      for (int n=0;n<4;n++)
        acc[n] = __builtin_amdgcn_mfma_f32_16x16x32_bf16(Breg[n][4+ks], b, acc[n], 0,0,0);
    }

    if (t+2 < T_){
      i32x2 p; p[0]=cvtpk(xvA[0],xvA[1]); p[1]=cvtpk(xvA[2],xvA[3]);
      *reinterpret_cast<i32x2*>(&xh[srow*XROW + cb*128 + schunk*4]) = p;
    }
    xvA = xvB;
    if (t+4 < T_){
      int tok = toks[srow*T_ + (dir ? (T_-5-t) : (t+4))];
      xvB = *reinterpret_cast<const f32x4*>(emb + tok*128 + schunk*4);
    }

    // Phase B: accx(t+1) = Wih @ x(t+1)
    if (t+1 < T_){
      #pragma unroll
      for (int n=0;n<4;n++) accx[n] = (f32x4){0.f,0.f,0.f,0.f};
      #pragma unroll
      for (int ks=0;ks<4;ks++){
        bf8 b = *reinterpret_cast<const bf8*>(&xh[mL*XROW + nb*128 + ks*32 + kb]);
        #pragma unroll
        for (int n=0;n<4;n++)
          accx[n] = __builtin_amdgcn_mfma_f32_16x16x32_bf16(Breg[n][ks], b, accx[n], 0,0,0);
      }
    }

    // cell update: fma-folded exp2 gates (R9/R10 verified, absmax 384)
    float hv4[4];
    #pragma unroll
    for (int i=0;i<4;i++){
      float si = __builtin_amdgcn_rcpf(1.f + exp2_(fmaf(acc[0][i], -L2E, sbias[0][i])));
      float sf = __builtin_amdgcn_rcpf(1.f + exp2_(fmaf(acc[1][i], -L2E, sbias[1][i])));
      float so = __builtin_amdgcn_rcpf(1.f + exp2_(fmaf(acc[3][i], -L2E, sbias[3][i])));
      float tg = 1.f - 2.f*__builtin_amdgcn_rcpf(exp2_(fmaf(acc[2][i], L2E2, sbias[2][i])) + 1.f);
      float c  = sf*cst[i] + si*tg;
      float th = 1.f - 2.f*__builtin_amdgcn_rcpf(exp2_(c*L2E2) + 1.f);
      float h  = so*th;
      cst[i]=c; hst[i]=h; hv4[i]=h;
    }
    if (t != T_-1){
      i32x2 hp;
      hp[0]=cvtpk(hv4[0],hv4[1]); hp[1]=cvtpk(hv4[2],hv4[3]);
      *reinterpret_cast<i32x2*>(&xh[mL*XROW + 256 + nb*128 + wave*16 + quad*4]) = hp;
      bar_lds();
    }
  }

  {
    const int ch = wave*16 + quad*4;
    const int gs = s0 + mL;
    i32x2 cp_, hp_;
    cp_[0]=cvtpk(cst[0],cst[1]); cp_[1]=cvtpk(cst[2],cst[3]);
    hp_[0]=cvtpk(hst[0],hst[1]); hp_[1]=cvtpk(hst[2],hst[3]);
    *reinterpret_cast<i32x2*>(c_cat + gs*256 + dir*128 + ch) = cp_;
    *reinterpret_cast<i32x2*>(h_cat + gs*256 + dir*128 + ch) = hp_;
  }
}

// ---------------------------------------------------------------------------
// Stage 2: enc_states -> hidden fp32 + bf16 mirror; row 0 zeroed.
// R10 shape: grid 96, m-split mt=1 (bit-exact K-order).
// ---------------------------------------------------------------------------
__global__ __launch_bounds__(256) void reduce_kernel(
    const u16* __restrict__ c_cat, const u16* __restrict__ h_cat,
    const u16* __restrict__ Wc, const float* __restrict__ bc,
    const u16* __restrict__ Whr, const float* __restrict__ bhr,
    float* __restrict__ hidf, u16* __restrict__ hidb)
{
  const int tid=threadIdx.x, wave=tid>>6, lane=tid&63;
  const int mL=lane&15, quad=lane>>4, kb=quad*8;
  const int m0 = blockIdx.x*16;
  const u16* A    = (wave<2) ? c_cat : h_cat;
  const u16* W    = (wave<2) ? Wc  : Whr;
  const float* bv = (wave<2) ? bc  : bhr;
  const int nb    = (wave&1)*64;
  const int obase = (wave<2) ? 0 : 128;

  f32x4 acc[4];
  #pragma unroll
  for (int nt=0;nt<4;nt++) acc[nt] = (f32x4){0.f,0.f,0.f,0.f};

  #pragma unroll
  for (int ks=0;ks<8;ks++){
    int k = ks*32 + kb;
    bf8 bfr[4];
    #pragma unroll
    for (int nt=0;nt<4;nt++)
      bfr[nt] = *reinterpret_cast<const bf8*>(W + (nb+nt*16+mL)*256 + k);
    bf8 a = *reinterpret_cast<const bf8*>(A + (m0+mL)*256 + k);
    #pragma unroll
    for (int nt=0;nt<4;nt++)
      acc[nt] = __builtin_amdgcn_mfma_f32_16x16x32_bf16(a, bfr[nt], acc[nt], 0,0,0);
  }
  const int row0 = quad*4;
  float biasv[4];
  #pragma unroll
  for (int nt=0;nt<4;nt++) biasv[nt] = bv[nb+nt*16+mL];
  #pragma unroll
  for (int nt=0;nt<4;nt++){
    int col = obase + nb + nt*16 + mL;
    #pragma unroll
    for (int i=0;i<4;i++){
      int r = m0 + row0 + i;
      float v = fmaxf(acc[nt][i] + biasv[nt], 0.f);
      hidf[(r+1)*256 + col] = v;
      hidb[(r+1)*256 + col] = f2bf(v);
    }
  }
  if (blockIdx.x==0 && tid<64){
    #pragma unroll
    for (int j=0;j<4;j++){ hidf[tid*4+j] = 0.f; hidb[tid*4+j] = 0; }
  }
}

// ---------------------------------------------------------------------------
// Stage 3 (x4): gi = hidden@Wi.T + bi, gh = hidden@Wh.T + bh  (bf16 tables)
// R7 shape: (49,12)x256, nt=2 -> 2.3 waves/SIMD.
// ---------------------------------------------------------------------------
__global__ __launch_bounds__(256) void gates_gemm_kernel(
    const u16* __restrict__ hidb,
    const u16* __restrict__ Wi, const u16* __restrict__ Wh,
    const float* __restrict__ bi, const float* __restrict__ bh,
    u16* __restrict__ gi, u16* __restrict__ gh)
{
  const int tid=threadIdx.x, wave=tid>>6, lane=tid&63;
  const int mL=lane&15, quad=lane>>4, kb=quad*8;
  const int m0 = blockIdx.x*32;
  const int n0 = blockIdx.y*128 + wave*32;   // blockIdx.y in [0,12)
  const bool isI = (n0 < 768);
  const u16* W    = isI ? Wi : Wh;
  const float* bv = isI ? bi : bh;
  u16* out        = isI ? gi : gh;
  const int nbc   = isI ? n0 : (n0-768);

  int arow[2];
  #pragma unroll
  for (int mt=0;mt<2;mt++) arow[mt] = min(m0+mt*16+mL, NR-1);

  f32x4 acc[2][2];
  #pragma unroll
  for (int mt=0;mt<2;mt++)
    #pragma unroll
    for (int nt=0;nt<2;nt++) acc[mt][nt] = (f32x4){0.f,0.f,0.f,0.f};

  #pragma unroll
  for (int ks=0;ks<8;ks++){
    int k = ks*32 + kb;
    bf8 bfr[2];
    #pragma unroll
    for (int nt=0;nt<2;nt++)
      bfr[nt] = *reinterpret_cast<const bf8*>(W + (nbc+nt*16+mL)*256 + k);
    #pragma unroll
    for (int mt=0;mt<2;mt++){
      bf8 a = *reinterpret_cast<const bf8*>(hidb + arow[mt]*256 + k);
      #pragma unroll
      for (int nt=0;nt<2;nt++)
        acc[mt][nt] = __builtin_amdgcn_mfma_f32_16x16x32_bf16(a, bfr[nt], acc[mt][nt], 0,0,0);
    }
  }
  const int row0 = quad*4;
  float biasv[2];
  #pragma unroll
  for (int nt=0;nt<2;nt++) biasv[nt] = bv[nbc+nt*16+mL];
  #pragma unroll
  for (int mt=0;mt<2;mt++){
    #pragma unroll
    for (int nt=0;nt<2;nt++){
      #pragma unroll
      for (int i=0;i<4;i++){
        int r = m0 + mt*16 + row0 + i;
        if (r < NR)
          out[r*768 + nbc + nt*16 + mL] = f2bf(acc[mt][nt][i] + biasv[nt]);
      }
    }
  }
}

// ---------------------------------------------------------------------------
// Stage 4 (x4): R2/R7 body (measured best) with BATCH->XCD AFFINITY SWIZZLE.
// Partner indices are batch-local (struct values = b*96+s+1 within batch b),
// so each row's gathers touch only its batch's ~800KB slice of gi/gh/hin.
// Default round-robin block->XCD spread every batch over every XCD: each
// 4MB per-XCD L2 tried to hold the full 6.2MB set -> thrash to IF/HBM.
// Remap: grid 1544 = 8 groups x 193; block (g = bid&7, j = bid>>3) handles
// r = 1 + (j<96 ? g*96+j : (g+8)*96+j-96)  [g==0,j==192 -> row 0; other
// g,j==192 exit]. Consecutive bids round-robin g, so XCD g sees only
// batches {g, g+8}. Pure index remap -> bit-exact per row.
// ---------------------------------------------------------------------------
__global__ __launch_bounds__(512) void pair_kernel(
    const u16* __restrict__ gi, const u16* __restrict__ gh,
    const float* __restrict__ hin,
    float* __restrict__ hout, u16* __restrict__ bout, float* __restrict__ dout,
    const int2* __restrict__ ent, const int* __restrict__ cnt)
{
  const int g = blockIdx.x & 7, j = blockIdx.x >> 3;
  int r;
  if (j == 192){
    if (g != 0) return;
    r = 0;
  } else {
    r = 1 + ((j < 96) ? (g*96 + j) : ((g+8)*96 + (j-96)));
  }
  const int tid = threadIdx.x, wave = tid>>6, lane = tid&63;
  __shared__ float part[8][260];
  __shared__ float ssum[4];
  if (r==0){
    if (tid<256){
      hout[tid]=0.f; bout[tid]=0;
      if (dout) dout[tid]=0.f;
    }
    return;
  }
  const int rr = r-1;
  const int n  = cnt[rr];
  const int2* e = ent + rr*S_;
  const int ch0 = lane*4;

  float a0=0.f, a1=0.f, a2=0.f, a3=0.f;
  for (int k=wave; k<n; k+=8){
    int2 pr = e[k];
    const u16* gx = gi + pr.x*768 + ch0;
    const u16* gy = gh + pr.y*768 + ch0;
    s16x4 vi0 = *reinterpret_cast<const s16x4*>(gx);
    s16x4 vi1 = *reinterpret_cast<const s16x4*>(gx+256);
    s16x4 vi2 = *reinterpret_cast<const s16x4*>(gx+512);
    s16x4 vh0 = *reinterpret_cast<const s16x4*>(gy);
    s16x4 vh1 = *reinterpret_cast<const s16x4*>(gy+256);
    s16x4 vh2 = *reinterpret_cast<const s16x4*>(gy+512);
    f32x4 hv  = *reinterpret_cast<const f32x4*>(hin + pr.y*256 + ch0);
    float o[4];
    #pragma unroll
    for (int i=0;i<4;i++){
      float rg = sigm(bf2f((u16)vi0[i]) + bf2f((u16)vh0[i]));
      float zg = sigm(bf2f((u16)vi1[i]) + bf2f((u16)vh1[i]));
      float ng = tanh_(bf2f((u16)vi2[i]) + rg*bf2f((u16)vh2[i]));
      o[i] = (1.f-zg)*ng + zg*hv[i];
    }
    a0 += o[0]; a1 += o[1]; a2 += o[2]; a3 += o[3];
  }
  *reinterpret_cast<f32x4*>(&part[wave][ch0]) = (f32x4){a0,a1,a2,a3};
  __syncthreads();

  if (tid < 256){
    float tot = part[0][tid] + part[1][tid] + part[2][tid] + part[3][tid]
              + part[4][tid] + part[5][tid] + part[6][tid] + part[7][tid];
    part[0][tid] = tot;                 // stash for epilogue
    float sq = tot*tot;
    #pragma unroll
    for (int off=32; off>0; off>>=1) sq += __shfl_xor(sq, off, 64);
    if (lane==0) ssum[wave] = sq;
  }
  __syncthreads();
  if (tid < 256){
    float tot = part[0][tid];
    float v  = sqrtf(ssum[0]+ssum[1]+ssum[2]+ssum[3]);
    float sc = (v + 0.25f)*__builtin_amdgcn_rcpf(v + 1.f);
    float nv = hin[r*256 + tid] + tot*sc;
    hout[r*256 + tid] = nv;
    bout[r*256 + tid] = f2bf(nv);
    if (dout) dout[r*256 + tid] = nv;
  }
}

// ---------------------------------------------------------------------------
extern "C" void kernel_launch(void* const* d_in, const int* in_sizes, int n_in,
                              void* d_out, int out_size, void* d_ws, size_t ws_size,
                              hipStream_t stream)
{
  const int*   enc  = (const int*)  d_in[0];
  const int*   spar = (const int*)  d_in[1];
  const int*   schi = (const int*)  d_in[2];
  const float* mask = (const float*)d_in[3];
  const float* emb  = (const float*)d_in[4];
  const float* WihF = (const float*)d_in[5];
  const float* WhhF = (const float*)d_in[6];
  const float* bF   = (const float*)d_in[7];
  const float* WihB = (const float*)d_in[8];
  const float* WhhB = (const float*)d_in[9];
  const float* bB   = (const float*)d_in[10];
  const float* Wc   = (const float*)d_in[11];
  const float* bc   = (const float*)d_in[12];
  const float* Whr  = (const float*)d_in[13];
  const float* bhr  = (const float*)d_in[14];
  const float* WiCP = (const float*)d_in[15];
  const float* WhCP = (const float*)d_in[16];
  const float* biCP = (const float*)d_in[17];
  const float* bhCP = (const float*)d_in[18];
  const float* WiPC = (const float*)d_in[19];
  const float* WhPC = (const float*)d_in[20];
  const float* biPC = (const float*)d_in[21];
  const float* bhPC = (const float*)d_in[22];

  // workspace layout (~14.8 MB)
  char* ws = (char*)d_ws;
  u16*   c_cat = (u16*)  (ws + 0);          // 1536*256 bf16
  u16*   h_cat = (u16*)  (ws + 786432);
  float* hf0   = (float*)(ws + 1572864);    // 1537*256 f32
  float* hf1   = (float*)(ws + 3146752);
  u16*   hb    = (u16*)  (ws + 4720640);    // 1537*256 bf16 (single buffer)
  u16*   gi    = (u16*)  (ws + 5507584);    // 1537*768 bf16
  u16*   gh    = (u16*)  (ws + 7868416);
  u16*   wbf   = (u16*)  (ws + 10229248);   // bf16 weights (1114112 elems)
  int2*  ent0  = (int2*) (ws + 12457472);   // 1536*96 int2
  int2*  ent1  = (int2*) (ws + 13637120);
  int*   cnt0  = (int*)  (ws + 14816768);
  int*   cnt1  = (int*)  (ws + 14822912);
  float* out   = (float*)d_out;

  u16* bWihF = wbf + 0;
  u16* bWhhF = wbf + 65536;
  u16* bWihB = wbf + 131072;
  u16* bWhhB = wbf + 196608;
  u16* bWc   = wbf + 262144;
  u16* bWhr  = wbf + 294912;
  u16* bWiCP = wbf + 327680;
  u16* bWhCP = wbf + 524288;
  u16* bWiPC = wbf + 720896;
  u16* bWhPC = wbf + 917504;

  CvtArgs ca;
  ca.s[0]=WihF; ca.s[1]=WhhF; ca.s[2]=WihB; ca.s[3]=WhhB;
  ca.s[4]=Wc;   ca.s[5]=Whr;
  ca.s[6]=WiCP; ca.s[7]=WhCP; ca.s[8]=WiPC; ca.s[9]=WhPC;
  ca.d[0]=bWihF; ca.d[1]=bWhhF; ca.d[2]=bWihB; ca.d[3]=bWhhB;
  ca.d[4]=bWc;   ca.d[5]=bWhr;
  ca.d[6]=bWiCP; ca.d[7]=bWhCP; ca.d[8]=bWiPC; ca.d[9]=bWhPC;
  prep_kernel<<<dim3(1088+NSEQ), dim3(256), 0, stream>>>(
      ca, spar, schi, mask, ent0, cnt0, ent1, cnt1);

  lstm_kernel<<<dim3(96,2), dim3(512), 0, stream>>>(
      enc, emb, bWihF,bWhhF,bF, bWihB,bWhhB,bB, c_cat, h_cat);
  reduce_kernel<<<dim3(96), dim3(256), 0, stream>>>(
      c_cat,h_cat, bWc,bc,bWhr,bhr, hf0,hb);

  float* hfb[2] = {hf0,hf1};
  int cur = 0;
  for (int it=0; it<4; it++){
    const u16* Wi   = (it<2)?bWiCP:bWiPC;
    const u16* Wh   = (it<2)?bWhCP:bWhPC;
    const float* bi = (it<2)?biCP:biPC;
    const float* bh = (it<2)?bhCP:bhPC;
    int nxt = cur^1;
    gates_gemm_kernel<<<dim3(49,12), dim3(256), 0, stream>>>(
        hb, Wi,Wh,bi,bh, gi,gh);
    pair_kernel<<<dim3(1544), dim3(512), 0, stream>>>(
        gi,gh, hfb[cur], hfb[nxt], hb,
        (it==3)?out:(float*)nullptr,
        (it<2)?ent0:ent1, (it<2)?cnt0:cnt1);
    cur = nxt;
  }
}

// Round 14
// 304.401 us; speedup vs baseline: 1.0493x; 1.0037x over previous
//
#include <hip/hip_runtime.h>

typedef unsigned short u16;
typedef __attribute__((ext_vector_type(8))) short bf8;    // 8 x bf16 MFMA fragment
typedef __attribute__((ext_vector_type(4))) short s16x4;
typedef __attribute__((ext_vector_type(4))) float f32x4;
typedef __attribute__((ext_vector_type(4))) int   i32x4;
typedef __attribute__((ext_vector_type(2))) int   i32x2;

#define S_   96
#define T_   50
#define NSEQ 1536
#define NR   1537
#define XROW 520   // LDS row stride in shorts: 1040 B, 16B-aligned, 260 dwords
#define L2E   1.4426950408889634f
#define L2E2  2.8853900817779268f

__device__ __forceinline__ float bf2f(u16 u){ return __uint_as_float(((unsigned)u)<<16); }
__device__ __forceinline__ u16 f2bf(float f){
  unsigned u = __float_as_uint(f);
  u += 0x7fffu + ((u>>16)&1u);           // RNE
  return (u16)(u>>16);
}
// packed f32x2 -> bf16x2 (RNE), single HW instruction; bit-identical to f2bf
__device__ __forceinline__ int cvtpk(float lo, float hi){
  int r; asm("v_cvt_pk_bf16_f32 %0, %1, %2" : "=v"(r) : "v"(lo), "v"(hi)); return r;
}
#if __has_builtin(__builtin_amdgcn_exp2f)
__device__ __forceinline__ float exp2_(float x){ return __builtin_amdgcn_exp2f(x); }
#else
__device__ __forceinline__ float exp2_(float x){ return exp2f(x); }
#endif
// division-free; fine vs 2% threshold, NaN-safe at +-inf
__device__ __forceinline__ float sigm(float x){
  return __builtin_amdgcn_rcpf(1.f + __expf(-x));
}
__device__ __forceinline__ float tanh_(float x){
  return 1.f - 2.f*__builtin_amdgcn_rcpf(__expf(2.f*x) + 1.f);
}
// barrier that drains only LDS (lgkm), NOT in-flight global prefetch (vmcnt).
__device__ __forceinline__ void bar_lds(){
  asm volatile("s_waitcnt lgkmcnt(0)\n\ts_barrier" ::: "memory");
}

// ---------------------------------------------------------------------------
// Stage 0 (fused): blocks [0,1088) convert fp32 weights to bf16 (LSTM weights
// row-permuted); blocks [1088, 1088+NSEQ) build compacted active-partner
// lists. NO pre-scaling of weights (R1 lesson: absmax headroom ~9%; bf16
// weight-bit changes are fatal). R11: fusing prep into lstm net-negative.
// ---------------------------------------------------------------------------
struct CvtArgs { const float* s[10]; u16* d[10]; };
__global__ __launch_bounds__(256) void prep_kernel(CvtArgs a,
    const int* __restrict__ par, const int* __restrict__ chi,
    const float* __restrict__ mask,
    int2* __restrict__ ent0, int* __restrict__ cnt0,
    int2* __restrict__ ent1, int* __restrict__ cnt1)
{
  if (blockIdx.x < 1088){
    int e = (blockIdx.x*256 + threadIdx.x)*4;
    if (e >= 1114112) return;
    int t, off;
    if (e < 262144){ t = e>>16; off = e & 65535; }
    else if (e < 327680){ int e2=e-262144; t = 4+(e2>>15); off = e2&32767; }
    else { int e3=e-327680; t = 6 + e3/196608; off = e3%196608; }
    int src = off;
    if (t < 4){
      int colp = off>>7, k = off&127;
      int orig = ((colp>>4)&3)*128 + ((colp>>6)<<4) + (colp&15);
      src = orig*128 + k;
    }
    f32x4 v = *reinterpret_cast<const f32x4*>(a.s[t]+src);
    i32x2 o;
    o[0] = cvtpk(v[0], v[1]);
    o[1] = cvtpk(v[2], v[3]);
    *reinterpret_cast<i32x2*>(a.d[t]+off) = o;
  } else {
    const int rr = blockIdx.x - 1088;
    __shared__ int c0s, c1s;
    if (threadIdx.x==0){ c0s=0; c1s=0; }
    __syncthreads();
    const int l = threadIdx.x;
    if (l < S_){
      const int b = rr/S_, fx = rr%S_, base = b*S_*S_;
      int idx = base + l*S_ + fx;
      if (mask[idx] != 0.f){
        int p = atomicAdd(&c0s, 1);
        ent0[rr*S_ + p] = make_int2(chi[idx], par[idx]);
      }
      int jdx = base + fx*S_ + l;
      if (mask[jdx] != 0.f){
        int p = atomicAdd(&c1s, 1);
        ent1[rr*S_ + p] = make_int2(par[jdx], chi[jdx]);
      }
    }
    __syncthreads();
    if (threadIdx.x==0){ cnt0[rr]=c0s; cnt1[rr]=c1s; }
  }
}

// ---------------------------------------------------------------------------
// Stage 1: bidirectional LSTM final states. R2 configuration (measured 70us
// after R9/R10 micro-opts): 16 seqs/block, 8 waves, grid (96,2)x512, weights
// register-resident (asm-pinned), K-split pipeline, lgkm-only barrier 1/step,
// fma-folded exp2 gates, Phase-A peel, dead-tail skip.
// R13 POST-MORTEM: hoisting cell+h-write above staging/Phase B produced
// NONDETERMINISTIC absmax failures (468/448) — a race I could not derive at
// source level. The reorder is condemned by measurement; this is the R12
// step order exactly (Phase A -> staging -> Phase B -> cell -> h-write ->
// barrier), which passed at 305.5us / absmax 384.
// R3/R4: dual-chain ILP structurally impossible (2x weight VGPR). R8/R9:
// grid-barrier fusion condemned. R11: fusions net-negative. R12: pair
// XCD-affinity null (latency-bound).
// ---------------------------------------------------------------------------
__global__ __launch_bounds__(512, 2) void lstm_kernel(
    const int* __restrict__ enc, const float* __restrict__ emb,
    const u16* __restrict__ WihF, const u16* __restrict__ WhhF, const float* __restrict__ bF,
    const u16* __restrict__ WihB, const u16* __restrict__ WhhB, const float* __restrict__ bB,
    u16* __restrict__ c_cat, u16* __restrict__ h_cat)
{
  __shared__ short xh[16*XROW];
  __shared__ int   toks[16*T_];

  const int tid  = threadIdx.x;
  const int wave = tid>>6;
  const int lane = tid&63;
  const int dir  = blockIdx.y;
  const int s0   = blockIdx.x*16;

  const u16* Wih = dir ? WihB : WihF;
  const u16* Whh = dir ? WhhB : WhhF;
  const float* bb = dir ? bB  : bF;

  for (int i=tid; i<16*T_; i+=512)
    toks[i] = enc[(s0 + i/T_)*T_ + (i%T_)];

  const int mL   = lane&15;
  const int quad = lane>>4;
  const int kb   = quad*8;

  // permuted weight fragments (A-operand layout), pinned.
  // Breg[n][0..3] = x-weights (k<128), Breg[n][4..7] = h-weights.
  // sbias[n] = bias*(-L2E) for i/f/o, bias*(2L2E) for g (f32-only; R9 opt).
  bf8 Breg[4][8];
  f32x4 sbias[4];
  #pragma unroll
  for (int n=0;n<4;n++){
    int colp = wave*64 + n*16 + mL;
    f32x4 bv = *reinterpret_cast<const f32x4*>(bb + n*128 + wave*16 + quad*4);
    float sc = (n==2) ? L2E2 : -L2E;
    #pragma unroll
    for (int i=0;i<4;i++) sbias[n][i] = bv[i]*sc;
    #pragma unroll
    for (int ks=0;ks<8;ks++){
      int k = ks*32 + kb;
      const u16* p = (k<128) ? (Wih + colp*128 + k) : (Whh + colp*128 + (k-128));
      Breg[n][ks] = *reinterpret_cast<const bf8*>(p);
      asm volatile("" : "+v"(Breg[n][ks]));
    }
  }

  if (tid<256){
    int r = tid>>4, c = tid&15;
    *reinterpret_cast<i32x4*>(&xh[r*XROW + 256 + c*8]) = (i32x4){0,0,0,0};
  }

  const int srow = tid>>5, schunk = tid&31;
  float cst[4] = {0.f,0.f,0.f,0.f};
  float hst[4] = {0.f,0.f,0.f,0.f};

  __syncthreads();

  {
    int tok0 = toks[srow*T_ + (dir ? (T_-1) : 0)];
    f32x4 x0 = *reinterpret_cast<const f32x4*>(emb + tok0*128 + schunk*4);
    int tok1 = toks[srow*T_ + (dir ? (T_-2) : 1)];
    f32x4 x1 = *reinterpret_cast<const f32x4*>(emb + tok1*128 + schunk*4);
    i32x2 p0; p0[0]=cvtpk(x0[0],x0[1]); p0[1]=cvtpk(x0[2],x0[3]);
    i32x2 p1; p1[0]=cvtpk(x1[0],x1[1]); p1[1]=cvtpk(x1[2],x1[3]);
    *reinterpret_cast<i32x2*>(&xh[srow*XROW +       schunk*4]) = p0;
    *reinterpret_cast<i32x2*>(&xh[srow*XROW + 128 + schunk*4]) = p1;
  }
  f32x4 xvA, xvB;
  {
    int tA = toks[srow*T_ + (dir ? (T_-3) : 2)];
    xvA = *reinterpret_cast<const f32x4*>(emb + tA*128 + schunk*4);
    int tB = toks[srow*T_ + (dir ? (T_-4) : 3)];
    xvB = *reinterpret_cast<const f32x4*>(emb + tB*128 + schunk*4);
  }
  __syncthreads();

  // pre-loop: accx(0) = Wih @ x(0)
  f32x4 accx[4];
  #pragma unroll
  for (int n=0;n<4;n++) accx[n] = (f32x4){0.f,0.f,0.f,0.f};
  #pragma unroll
  for (int ks=0;ks<4;ks++){
    bf8 b = *reinterpret_cast<const bf8*>(&xh[mL*XROW + ks*32 + kb]);
    #pragma unroll
    for (int n=0;n<4;n++)
      accx[n] = __builtin_amdgcn_mfma_f32_16x16x32_bf16(Breg[n][ks], b, accx[n], 0,0,0);
  }
  bar_lds();  // RACE FIX: pre-loop x-slot-0 reads before step-0 restage.

  for (int t=0;t<T_;t++){
    const int cb = t&1, nb = cb^1;

    // Phase A: gates(t) = accx(t) + Whh @ h(t-1); first MFMA takes accx as
    // C-in (peel) — identical accumulation chain, no copies.
    f32x4 acc[4];
    {
      bf8 b = *reinterpret_cast<const bf8*>(&xh[mL*XROW + 256 + cb*128 + kb]);
      #pragma unroll
      for (int n=0;n<4;n++)
        acc[n] = __builtin_amdgcn_mfma_f32_16x16x32_bf16(Breg[n][4], b, accx[n], 0,0,0);
    }
    #pragma unroll
    for (int ks=1;ks<4;ks++){
      bf8 b = *reinterpret_cast<const bf8*>(&xh[mL*XROW + 256 + cb*128 + ks*32 + kb]);
      #pragma unroll
      for (int n=0;n<4;n++)
        acc[n] = __builtin_amdgcn_mfma_f32_16x16x32_bf16(Breg[n][4+ks], b, acc[n], 0,0,0);
    }

    // stage x(t+2) into slot (t+2)&1 == cb (vacated; last read barrier-sep'd)
    if (t+2 < T_){
      i32x2 p; p[0]=cvtpk(xvA[0],xvA[1]); p[1]=cvtpk(xvA[2],xvA[3]);
      *reinterpret_cast<i32x2*>(&xh[srow*XROW + cb*128 + schunk*4]) = p;
    }
    xvA = xvB;
    if (t+4 < T_){
      int tok = toks[srow*T_ + (dir ? (T_-5-t) : (t+4))];
      xvB = *reinterpret_cast<const f32x4*>(emb + tok*128 + schunk*4);
    }

    // Phase B: accx(t+1) = Wih @ x(t+1)  (independent of the recurrence)
    if (t+1 < T_){
      #pragma unroll
      for (int n=0;n<4;n++) accx[n] = (f32x4){0.f,0.f,0.f,0.f};
      #pragma unroll
      for (int ks=0;ks<4;ks++){
        bf8 b = *reinterpret_cast<const bf8*>(&xh[mL*XROW + nb*128 + ks*32 + kb]);
        #pragma unroll
        for (int n=0;n<4;n++)
          accx[n] = __builtin_amdgcn_mfma_f32_16x16x32_bf16(Breg[n][ks], b, accx[n], 0,0,0);
      }
    }

    // cell update: fma-folded exp2 gates (R9/R10 verified, absmax 384)
    float hv4[4];
    #pragma unroll
    for (int i=0;i<4;i++){
      float si = __builtin_amdgcn_rcpf(1.f + exp2_(fmaf(acc[0][i], -L2E, sbias[0][i])));
      float sf = __builtin_amdgcn_rcpf(1.f + exp2_(fmaf(acc[1][i], -L2E, sbias[1][i])));
      float so = __builtin_amdgcn_rcpf(1.f + exp2_(fmaf(acc[3][i], -L2E, sbias[3][i])));
      float tg = 1.f - 2.f*__builtin_amdgcn_rcpf(exp2_(fmaf(acc[2][i], L2E2, sbias[2][i])) + 1.f);
      float c  = sf*cst[i] + si*tg;
      float th = 1.f - 2.f*__builtin_amdgcn_rcpf(exp2_(c*L2E2) + 1.f);
      float h  = so*th;
      cst[i]=c; hst[i]=h; hv4[i]=h;
    }
    if (t != T_-1){
      i32x2 hp;
      hp[0]=cvtpk(hv4[0],hv4[1]); hp[1]=cvtpk(hv4[2],hv4[3]);
      *reinterpret_cast<i32x2*>(&xh[mL*XROW + 256 + nb*128 + wave*16 + quad*4]) = hp;
      bar_lds();
    }
  }

  {
    const int ch = wave*16 + quad*4;
    const int gs = s0 + mL;
    i32x2 cp_, hp_;
    cp_[0]=cvtpk(cst[0],cst[1]); cp_[1]=cvtpk(cst[2],cst[3]);
    hp_[0]=cvtpk(hst[0],hst[1]); hp_[1]=cvtpk(hst[2],hst[3]);
    *reinterpret_cast<i32x2*>(c_cat + gs*256 + dir*128 + ch) = cp_;
    *reinterpret_cast<i32x2*>(h_cat + gs*256 + dir*128 + ch) = hp_;
  }
}

// ---------------------------------------------------------------------------
// Stage 2: enc_states -> hidden fp32 + bf16 mirror; row 0 zeroed.
// R10 shape: grid 96, m-split mt=1 (bit-exact K-order).
// ---------------------------------------------------------------------------
__global__ __launch_bounds__(256) void reduce_kernel(
    const u16* __restrict__ c_cat, const u16* __restrict__ h_cat,
    const u16* __restrict__ Wc, const float* __restrict__ bc,
    const u16* __restrict__ Whr, const float* __restrict__ bhr,
    float* __restrict__ hidf, u16* __restrict__ hidb)
{
  const int tid=threadIdx.x, wave=tid>>6, lane=tid&63;
  const int mL=lane&15, quad=lane>>4, kb=quad*8;
  const int m0 = blockIdx.x*16;
  const u16* A    = (wave<2) ? c_cat : h_cat;
  const u16* W    = (wave<2) ? Wc  : Whr;
  const float* bv = (wave<2) ? bc  : bhr;
  const int nb    = (wave&1)*64;
  const int obase = (wave<2) ? 0 : 128;

  f32x4 acc[4];
  #pragma unroll
  for (int nt=0;nt<4;nt++) acc[nt] = (f32x4){0.f,0.f,0.f,0.f};

  #pragma unroll
  for (int ks=0;ks<8;ks++){
    int k = ks*32 + kb;
    bf8 bfr[4];
    #pragma unroll
    for (int nt=0;nt<4;nt++)
      bfr[nt] = *reinterpret_cast<const bf8*>(W + (nb+nt*16+mL)*256 + k);
    bf8 a = *reinterpret_cast<const bf8*>(A + (m0+mL)*256 + k);
    #pragma unroll
    for (int nt=0;nt<4;nt++)
      acc[nt] = __builtin_amdgcn_mfma_f32_16x16x32_bf16(a, bfr[nt], acc[nt], 0,0,0);
  }
  const int row0 = quad*4;
  float biasv[4];
  #pragma unroll
  for (int nt=0;nt<4;nt++) biasv[nt] = bv[nb+nt*16+mL];
  #pragma unroll
  for (int nt=0;nt<4;nt++){
    int col = obase + nb + nt*16 + mL;
    #pragma unroll
    for (int i=0;i<4;i++){
      int r = m0 + row0 + i;
      float v = fmaxf(acc[nt][i] + biasv[nt], 0.f);
      hidf[(r+1)*256 + col] = v;
      hidb[(r+1)*256 + col] = f2bf(v);
    }
  }
  if (blockIdx.x==0 && tid<64){
    #pragma unroll
    for (int j=0;j<4;j++){ hidf[tid*4+j] = 0.f; hidb[tid*4+j] = 0; }
  }
}

// ---------------------------------------------------------------------------
// Stage 3 (x4): gi = hidden@Wi.T + bi, gh = hidden@Wh.T + bh  (bf16 tables)
// R7 shape: (49,12)x256, nt=2 -> 2.3 waves/SIMD.
// ---------------------------------------------------------------------------
__global__ __launch_bounds__(256) void gates_gemm_kernel(
    const u16* __restrict__ hidb,
    const u16* __restrict__ Wi, const u16* __restrict__ Wh,
    const float* __restrict__ bi, const float* __restrict__ bh,
    u16* __restrict__ gi, u16* __restrict__ gh)
{
  const int tid=threadIdx.x, wave=tid>>6, lane=tid&63;
  const int mL=lane&15, quad=lane>>4, kb=quad*8;
  const int m0 = blockIdx.x*32;
  const int n0 = blockIdx.y*128 + wave*32;   // blockIdx.y in [0,12)
  const bool isI = (n0 < 768);
  const u16* W    = isI ? Wi : Wh;
  const float* bv = isI ? bi : bh;
  u16* out        = isI ? gi : gh;
  const int nbc   = isI ? n0 : (n0-768);

  int arow[2];
  #pragma unroll
  for (int mt=0;mt<2;mt++) arow[mt] = min(m0+mt*16+mL, NR-1);

  f32x4 acc[2][2];
  #pragma unroll
  for (int mt=0;mt<2;mt++)
    #pragma unroll
    for (int nt=0;nt<2;nt++) acc[mt][nt] = (f32x4){0.f,0.f,0.f,0.f};

  #pragma unroll
  for (int ks=0;ks<8;ks++){
    int k = ks*32 + kb;
    bf8 bfr[2];
    #pragma unroll
    for (int nt=0;nt<2;nt++)
      bfr[nt] = *reinterpret_cast<const bf8*>(W + (nbc+nt*16+mL)*256 + k);
    #pragma unroll
    for (int mt=0;mt<2;mt++){
      bf8 a = *reinterpret_cast<const bf8*>(hidb + arow[mt]*256 + k);
      #pragma unroll
      for (int nt=0;nt<2;nt++)
        acc[mt][nt] = __builtin_amdgcn_mfma_f32_16x16x32_bf16(a, bfr[nt], acc[mt][nt], 0,0,0);
    }
  }
  const int row0 = quad*4;
  float biasv[2];
  #pragma unroll
  for (int nt=0;nt<2;nt++) biasv[nt] = bv[nbc+nt*16+mL];
  #pragma unroll
  for (int mt=0;mt<2;mt++){
    #pragma unroll
    for (int nt=0;nt<2;nt++){
      #pragma unroll
      for (int i=0;i<4;i++){
        int r = m0 + mt*16 + row0 + i;
        if (r < NR)
          out[r*768 + nbc + nt*16 + mL] = f2bf(acc[mt][nt][i] + biasv[nt]);
      }
    }
  }
}

// ---------------------------------------------------------------------------
// Stage 4 (x4): R2/R7 body with batch->XCD affinity remap (R12: ~neutral but
// kept — marginally best measured config). Block per output row; partners
// split across 8 waves; GRU elementwise fp32; LDS cross-wave sum; L2-norm
// scale; double-buffered hidden update.
// ---------------------------------------------------------------------------
__global__ __launch_bounds__(512) void pair_kernel(
    const u16* __restrict__ gi, const u16* __restrict__ gh,
    const float* __restrict__ hin,
    float* __restrict__ hout, u16* __restrict__ bout, float* __restrict__ dout,
    const int2* __restrict__ ent, const int* __restrict__ cnt)
{
  const int g = blockIdx.x & 7, j = blockIdx.x >> 3;
  int r;
  if (j == 192){
    if (g != 0) return;
    r = 0;
  } else {
    r = 1 + ((j < 96) ? (g*96 + j) : ((g+8)*96 + (j-96)));
  }
  const int tid = threadIdx.x, wave = tid>>6, lane = tid&63;
  __shared__ float part[8][260];
  __shared__ float ssum[4];
  if (r==0){
    if (tid<256){
      hout[tid]=0.f; bout[tid]=0;
      if (dout) dout[tid]=0.f;
    }
    return;
  }
  const int rr = r-1;
  const int n  = cnt[rr];
  const int2* e = ent + rr*S_;
  const int ch0 = lane*4;

  float a0=0.f, a1=0.f, a2=0.f, a3=0.f;
  for (int k=wave; k<n; k+=8){
    int2 pr = e[k];
    const u16* gx = gi + pr.x*768 + ch0;
    const u16* gy = gh + pr.y*768 + ch0;
    s16x4 vi0 = *reinterpret_cast<const s16x4*>(gx);
    s16x4 vi1 = *reinterpret_cast<const s16x4*>(gx+256);
    s16x4 vi2 = *reinterpret_cast<const s16x4*>(gx+512);
    s16x4 vh0 = *reinterpret_cast<const s16x4*>(gy);
    s16x4 vh1 = *reinterpret_cast<const s16x4*>(gy+256);
    s16x4 vh2 = *reinterpret_cast<const s16x4*>(gy+512);
    f32x4 hv  = *reinterpret_cast<const f32x4*>(hin + pr.y*256 + ch0);
    float o[4];
    #pragma unroll
    for (int i=0;i<4;i++){
      float rg = sigm(bf2f((u16)vi0[i]) + bf2f((u16)vh0[i]));
      float zg = sigm(bf2f((u16)vi1[i]) + bf2f((u16)vh1[i]));
      float ng = tanh_(bf2f((u16)vi2[i]) + rg*bf2f((u16)vh2[i]));
      o[i] = (1.f-zg)*ng + zg*hv[i];
    }
    a0 += o[0]; a1 += o[1]; a2 += o[2]; a3 += o[3];
  }
  *reinterpret_cast<f32x4*>(&part[wave][ch0]) = (f32x4){a0,a1,a2,a3};
  __syncthreads();

  if (tid < 256){
    float tot = part[0][tid] + part[1][tid] + part[2][tid] + part[3][tid]
              + part[4][tid] + part[5][tid] + part[6][tid] + part[7][tid];
    part[0][tid] = tot;                 // stash for epilogue
    float sq = tot*tot;
    #pragma unroll
    for (int off=32; off>0; off>>=1) sq += __shfl_xor(sq, off, 64);
    if (lane==0) ssum[wave] = sq;
  }
  __syncthreads();
  if (tid < 256){
    float tot = part[0][tid];
    float v  = sqrtf(ssum[0]+ssum[1]+ssum[2]+ssum[3]);
    float sc = (v + 0.25f)*__builtin_amdgcn_rcpf(v + 1.f);
    float nv = hin[r*256 + tid] + tot*sc;
    hout[r*256 + tid] = nv;
    bout[r*256 + tid] = f2bf(nv);
    if (dout) dout[r*256 + tid] = nv;
  }
}

// ---------------------------------------------------------------------------
extern "C" void kernel_launch(void* const* d_in, const int* in_sizes, int n_in,
                              void* d_out, int out_size, void* d_ws, size_t ws_size,
                              hipStream_t stream)
{
  const int*   enc  = (const int*)  d_in[0];
  const int*   spar = (const int*)  d_in[1];
  const int*   schi = (const int*)  d_in[2];
  const float* mask = (const float*)d_in[3];
  const float* emb  = (const float*)d_in[4];
  const float* WihF = (const float*)d_in[5];
  const float* WhhF = (const float*)d_in[6];
  const float* bF   = (const float*)d_in[7];
  const float* WihB = (const float*)d_in[8];
  const float* WhhB = (const float*)d_in[9];
  const float* bB   = (const float*)d_in[10];
  const float* Wc   = (const float*)d_in[11];
  const float* bc   = (const float*)d_in[12];
  const float* Whr  = (const float*)d_in[13];
  const float* bhr  = (const float*)d_in[14];
  const float* WiCP = (const float*)d_in[15];
  const float* WhCP = (const float*)d_in[16];
  const float* biCP = (const float*)d_in[17];
  const float* bhCP = (const float*)d_in[18];
  const float* WiPC = (const float*)d_in[19];
  const float* WhPC = (const float*)d_in[20];
  const float* biPC = (const float*)d_in[21];
  const float* bhPC = (const float*)d_in[22];

  // workspace layout (~14.8 MB)
  char* ws = (char*)d_ws;
  u16*   c_cat = (u16*)  (ws + 0);          // 1536*256 bf16
  u16*   h_cat = (u16*)  (ws + 786432);
  float* hf0   = (float*)(ws + 1572864);    // 1537*256 f32
  float* hf1   = (float*)(ws + 3146752);
  u16*   hb    = (u16*)  (ws + 4720640);    // 1537*256 bf16 (single buffer)
  u16*   gi    = (u16*)  (ws + 5507584);    // 1537*768 bf16
  u16*   gh    = (u16*)  (ws + 7868416);
  u16*   wbf   = (u16*)  (ws + 10229248);   // bf16 weights (1114112 elems)
  int2*  ent0  = (int2*) (ws + 12457472);   // 1536*96 int2
  int2*  ent1  = (int2*) (ws + 13637120);
  int*   cnt0  = (int*)  (ws + 14816768);
  int*   cnt1  = (int*)  (ws + 14822912);
  float* out   = (float*)d_out;

  u16* bWihF = wbf + 0;
  u16* bWhhF = wbf + 65536;
  u16* bWihB = wbf + 131072;
  u16* bWhhB = wbf + 196608;
  u16* bWc   = wbf + 262144;
  u16* bWhr  = wbf + 294912;
  u16* bWiCP = wbf + 327680;
  u16* bWhCP = wbf + 524288;
  u16* bWiPC = wbf + 720896;
  u16* bWhPC = wbf + 917504;

  CvtArgs ca;
  ca.s[0]=WihF; ca.s[1]=WhhF; ca.s[2]=WihB; ca.s[3]=WhhB;
  ca.s[4]=Wc;   ca.s[5]=Whr;
  ca.s[6]=WiCP; ca.s[7]=WhCP; ca.s[8]=WiPC; ca.s[9]=WhPC;
  ca.d[0]=bWihF; ca.d[1]=bWhhF; ca.d[2]=bWihB; ca.d[3]=bWhhB;
  ca.d[4]=bWc;   ca.d[5]=bWhr;
  ca.d[6]=bWiCP; ca.d[7]=bWhCP; ca.d[8]=bWiPC; ca.d[9]=bWhPC;
  prep_kernel<<<dim3(1088+NSEQ), dim3(256), 0, stream>>>(
      ca, spar, schi, mask, ent0, cnt0, ent1, cnt1);

  lstm_kernel<<<dim3(96,2), dim3(512), 0, stream>>>(
      enc, emb, bWihF,bWhhF,bF, bWihB,bWhhB,bB, c_cat, h_cat);
  reduce_kernel<<<dim3(96), dim3(256), 0, stream>>>(
      c_cat,h_cat, bWc,bc,bWhr,bhr, hf0,hb);

  float* hfb[2] = {hf0,hf1};
  int cur = 0;
  for (int it=0; it<4; it++){
    const u16* Wi   = (it<2)?bWiCP:bWiPC;
    const u16* Wh   = (it<2)?bWhCP:bWhPC;
    const float* bi = (it<2)?biCP:biPC;
    const float* bh = (it<2)?bhCP:bhPC;
    int nxt = cur^1;
    gates_gemm_kernel<<<dim3(49,12), dim3(256), 0, stream>>>(
        hb, Wi,Wh,bi,bh, gi,gh);
    pair_kernel<<<dim3(1544), dim3(512), 0, stream>>>(
        gi,gh, hfb[cur], hfb[nxt], hb,
        (it==3)?out:(float*)nullptr,
        (it<2)?ent0:ent1, (it<2)?cnt0:cnt1);
    cur = nxt;
  }
}